// Round 9
// baseline (431.846 us; speedup 1.0000x reference)
//
#include <hip/hip_runtime.h>
#include <hip/hip_bf16.h>

// SAGE 2-layer: N nodes, E edges, D=256. FP32 inputs, bf16 MFMA pipeline.
// R8->R9: agg (fabric-bound, 54us) and gemm (latency-bound, 56us) were
// serial per layer. Fused sage_layer_kernel: per 64-row block, phase 1
// gathers mean(nbrs) into an LDS A-tile (Ms, staged-As-compatible XOR
// layout); phase 2 runs the concat-GEMM (K 0..255 = mean from Ms,
// K 256..511 = x/h staged via global_load_lds) + bias + L2norm (+relu).
// 72.3KB LDS -> 2 blocks/CU co-resident: gather and MFMA phases overlap
// across blocks. Mean buffer round-trip and 2 dispatches eliminated.
//
// CSR build: count -> 2-stage scan -> counting-sort (part/group, R8).

#define DD 256
#define NPB 128          // nodes per bucket (dst >> 7)

typedef unsigned short ushort_t;
using bf16x8 = __attribute__((ext_vector_type(8))) short;
using f32x4  = __attribute__((ext_vector_type(4))) float;

static __device__ __forceinline__ float b2f(ushort_t u) {
    __hip_bfloat16 h = *reinterpret_cast<__hip_bfloat16*>(&u);
    return __bfloat162float(h);
}
static __device__ __forceinline__ ushort_t f2b(float f) {
    __hip_bfloat16 h = __float2bfloat16(f);
    return *reinterpret_cast<ushort_t*>(&h);
}

static __device__ __forceinline__ void load16(const ushort_t* g, ushort_t* l) {
    __builtin_amdgcn_global_load_lds(
        (const __attribute__((address_space(1))) unsigned*)(g),
        (__attribute__((address_space(3))) unsigned*)(l),
        16, 0, 0);
}

// ---------------- fused prep: count + cast_x + cast_w ----------------

__global__ __launch_bounds__(256) void prep_kernel(
        const int* __restrict__ ei, int* __restrict__ cnt, int E, int eb,
        const float* __restrict__ x, ushort_t* __restrict__ xb, int xe, int cxb,
        const float* __restrict__ w1l, const float* __restrict__ w1r,
        const float* __restrict__ w2l, const float* __restrict__ w2r,
        ushort_t* __restrict__ wc1, ushort_t* __restrict__ wc2) {
    int b = blockIdx.x;
    if (b < eb) {
        int e = b * 256 + threadIdx.x;
        if (e < E) atomicAdd(&cnt[ei[E + e]], 1);   // dst row = second row
        return;
    }
    b -= eb;
    if (b < cxb) {
        int i = (b * 256 + threadIdx.x) * 8;
        if (i + 8 > xe) return;
        float4 a = *(const float4*)(x + i);
        float4 c = *(const float4*)(x + i + 4);
        ushort_t o[8] = {f2b(a.x), f2b(a.y), f2b(a.z), f2b(a.w),
                         f2b(c.x), f2b(c.y), f2b(c.z), f2b(c.w)};
        *(int4*)(xb + i) = *(const int4*)o;
        return;
    }
    b -= cxb;
    {
        int i = (b * 256 + threadIdx.x) * 8;        // 0 .. 4*65536
        int which = i >> 16;                        // 0=W1l 1=W1r 2=W2l 3=W2r
        int o = i & 65535;
        int row = o >> 8, col = o & 255;
        const float* src = (which == 0) ? w1l : (which == 1) ? w1r
                          : (which == 2) ? w2l : w2r;
        ushort_t* dst = ((which < 2) ? wc1 : wc2)
                        + (size_t)row * 512 + (which & 1) * 256 + col;
        float4 a = *(const float4*)(src + o);
        float4 c = *(const float4*)(src + o + 4);
        ushort_t ov[8] = {f2b(a.x), f2b(a.y), f2b(a.z), f2b(a.w),
                          f2b(c.x), f2b(c.y), f2b(c.z), f2b(c.w)};
        *(int4*)dst = *(const int4*)ov;
    }
}

// ---------------- scan ----------------

__global__ __launch_bounds__(256) void scan_partial_kernel(const int* __restrict__ cnt,
                                                           int* __restrict__ part, int n) {
    __shared__ int ws[4];
    int tid = threadIdx.x;
    int wave = tid >> 6, lane = tid & 63;
    int i0 = blockIdx.x * 2048 + tid * 8;
    int sum = 0;
    if (i0 + 8 <= n) {
        int4 a = *(const int4*)(cnt + i0);
        int4 b = *(const int4*)(cnt + i0 + 4);
        sum = a.x + a.y + a.z + a.w + b.x + b.y + b.z + b.w;
    } else {
        for (int j = i0; j < n; j++) sum += cnt[j];
    }
    #pragma unroll
    for (int off = 1; off < 64; off <<= 1) sum += __shfl_xor(sum, off);
    if (lane == 0) ws[wave] = sum;
    __syncthreads();
    if (tid == 0) part[blockIdx.x] = ws[0] + ws[1] + ws[2] + ws[3];
}

// local rescan + inline partial-scan -> offs; seeds bcur[b]=offs[b*NPB].
__global__ __launch_bounds__(256) void scan_final_kernel(const int* __restrict__ cnt,
                                                         const int* __restrict__ part,
                                                         int* __restrict__ offs,
                                                         int* __restrict__ bcur,
                                                         int n, int E, int nb) {
    __shared__ int wt[4];
    __shared__ int sbase;
    int tid = threadIdx.x;
    int wave = tid >> 6, lane = tid & 63;
    if (tid < 64) {
        int pv = (tid < nb) ? part[tid] : 0;
        int incl = pv;
        #pragma unroll
        for (int off = 1; off < 64; off <<= 1) {
            int t = __shfl_up(incl, off);
            if (tid >= off) incl += t;
        }
        if (tid == (int)blockIdx.x) sbase = incl - pv;
    }
    int i0 = blockIdx.x * 2048 + tid * 8;
    int v[8], s[8];
    int run = 0;
    if (i0 + 8 <= n) {
        int4 a = *(const int4*)(cnt + i0);
        int4 b = *(const int4*)(cnt + i0 + 4);
        v[0] = a.x; v[1] = a.y; v[2] = a.z; v[3] = a.w;
        v[4] = b.x; v[5] = b.y; v[6] = b.z; v[7] = b.w;
    } else {
        #pragma unroll
        for (int j = 0; j < 8; j++) v[j] = (i0 + j < n) ? cnt[i0 + j] : 0;
    }
    #pragma unroll
    for (int j = 0; j < 8; j++) { run += v[j]; s[j] = run; }
    int tsum = run;
    int incl = tsum;
    #pragma unroll
    for (int off = 1; off < 64; off <<= 1) {
        int t = __shfl_up(incl, off);
        if (lane >= off) incl += t;
    }
    if (lane == 63) wt[wave] = incl;
    __syncthreads();
    int woff = 0;
    for (int w = 0; w < wave; w++) woff += wt[w];
    int texcl = sbase + woff + (incl - tsum);
    #pragma unroll
    for (int j = 0; j < 8; j++) {
        int idx = i0 + j;
        if (idx < n) {
            int e = texcl + s[j] - v[j];
            offs[idx] = e;
            if ((idx & (NPB - 1)) == 0) bcur[idx / NPB] = e;
        }
    }
    if (blockIdx.x == 0 && tid == 0) offs[n] = E;
}

// ---------------- CSR build: 2-pass counting sort ----------------

__global__ __launch_bounds__(256) void part_kernel(const int* __restrict__ ei,
                                                   int* __restrict__ bcur,
                                                   int2* __restrict__ stage,
                                                   int E, int nbuck) {
    __shared__ int hist[512];
    __shared__ int gbase[512];
    int tid = threadIdx.x;
    for (int i = tid; i < nbuck; i += 256) hist[i] = 0;
    __syncthreads();
    int sv[8], dv[8], bk[8], rk[8];
    #pragma unroll
    for (int j = 0; j < 8; j++) {
        int e = blockIdx.x * 2048 + j * 256 + tid;
        if (e < E) {
            sv[j] = ei[e];
            dv[j] = ei[E + e];
            bk[j] = dv[j] / NPB;
            rk[j] = atomicAdd(&hist[bk[j]], 1);
        } else bk[j] = -1;
    }
    __syncthreads();
    for (int i = tid; i < nbuck; i += 256) {
        int h = hist[i];
        gbase[i] = h ? atomicAdd(&bcur[i], h) : 0;
    }
    __syncthreads();
    #pragma unroll
    for (int j = 0; j < 8; j++)
        if (bk[j] >= 0) {
            int p = gbase[bk[j]] + rk[j];
            stage[p] = make_int2(sv[j], dv[j]);
        }
}

__global__ __launch_bounds__(256) void group_kernel(const int2* __restrict__ stage,
                                                    const int* __restrict__ offs,
                                                    int* __restrict__ csr, int N) {
    __shared__ int lcur[NPB];
    int b = blockIdx.x;
    int lo = b * NPB;
    int hi = min(N, lo + NPB);
    int tid = threadIdx.x;
    if (tid < hi - lo) lcur[tid] = offs[lo + tid];
    __syncthreads();
    int base = offs[lo];
    int m = offs[hi] - base;
    for (int t = tid; t < m; t += 256) {
        int2 v = stage[base + t];
        int p = atomicAdd(&lcur[v.y - lo], 1);
        csr[p] = v.x;
    }
}

// ---------------- fused SAGE layer: gather-mean + GEMM + bias + norm ----------------
// Block = 64 dst rows, 256 threads / 4 waves. LDS:
//   Ms[4][64x64]  mean A-tiles (XOR-chunk layout == staged-As addressing), 32KB
//   As[64x64]     x-half staging tile, 8KB
//   Bs[256x64]    W staging tile, 32KB
//   ebuf          epilogue transpose (union with the above), 33.8KB
// Phase 1: wave wv gathers nodes wv*16..+16 (halves = nbr parity, 32 dim
// chunks), writes bf16 means into Ms. Phase 2: K-iters 0..3 read A-frags
// from Ms, 4..7 stage x/h from global; Bs staged every iter (W k=0..511).

__global__ __launch_bounds__(256, 2) void sage_layer_kernel(
        const ushort_t* __restrict__ xsrc,  // [N,256] bf16 (x or h)
        const int* __restrict__ csr,
        const int* __restrict__ offs,
        const ushort_t* __restrict__ W,     // [256,512] bf16 (Wl | Wr)
        const float*    __restrict__ bias,  // [256] fp32
        ushort_t* __restrict__ outb,        // bf16 out, or null
        float*    __restrict__ outf,        // fp32 out, or null
        int N, int relu) {
    __shared__ union {
        struct {
            ushort_t Ms[4 * 4096];   // 32 KB
            ushort_t As[64 * 64];    // 8 KB
            ushort_t Bs[256 * 64];   // 32 KB
        } s;
        ushort_t ebuf[64 * 264];     // 33.8 KB
    } u;
    __shared__ float rowsq[64];

    int tid = threadIdx.x;
    int wave = tid >> 6, lane = tid & 63;
    int quad = lane >> 4, m16 = lane & 15;
    int swz = m16 & 7;
    int rowbase = blockIdx.x * 64;

    if (tid < 64) rowsq[tid] = 0.f;

    // ---------- phase 1: gather mean for rows wave*16 .. +16 ----------
    {
        int half = lane >> 5;           // neighbor parity
        int c = lane & 31;              // dim chunk (8 bf16)
        const ushort_t* base = xsrc + (size_t)c * 8;
        for (int j = 0; j < 16; j++) {
            int r = wave * 16 + j;
            int node = rowbase + r;
            if (node >= N) break;
            int beg = offs[node], end = offs[node + 1];
            float acc[8];
            #pragma unroll
            for (int q = 0; q < 8; q++) acc[q] = 0.f;
            int i = beg;
            for (; i + 8 <= end; i += 8) {
                int s0 = csr[i + half];
                int s1 = csr[i + 2 + half];
                int s2 = csr[i + 4 + half];
                int s3 = csr[i + 6 + half];
                int4 v0 = *(const int4*)(base + (size_t)s0 * 256);
                int4 v1 = *(const int4*)(base + (size_t)s1 * 256);
                int4 v2 = *(const int4*)(base + (size_t)s2 * 256);
                int4 v3 = *(const int4*)(base + (size_t)s3 * 256);
                {   const unsigned* uu = (const unsigned*)&v0;
                    #pragma unroll
                    for (int q = 0; q < 4; q++) {
                        acc[2*q]   += __uint_as_float(uu[q] << 16);
                        acc[2*q+1] += __uint_as_float(uu[q] & 0xffff0000u);
                    } }
                {   const unsigned* uu = (const unsigned*)&v1;
                    #pragma unroll
                    for (int q = 0; q < 4; q++) {
                        acc[2*q]   += __uint_as_float(uu[q] << 16);
                        acc[2*q+1] += __uint_as_float(uu[q] & 0xffff0000u);
                    } }
                {   const unsigned* uu = (const unsigned*)&v2;
                    #pragma unroll
                    for (int q = 0; q < 4; q++) {
                        acc[2*q]   += __uint_as_float(uu[q] << 16);
                        acc[2*q+1] += __uint_as_float(uu[q] & 0xffff0000u);
                    } }
                {   const unsigned* uu = (const unsigned*)&v3;
                    #pragma unroll
                    for (int q = 0; q < 4; q++) {
                        acc[2*q]   += __uint_as_float(uu[q] << 16);
                        acc[2*q+1] += __uint_as_float(uu[q] & 0xffff0000u);
                    } }
            }
            for (; i + 2 <= end; i += 2) {
                int s0 = csr[i + half];
                int4 v0 = *(const int4*)(base + (size_t)s0 * 256);
                const unsigned* uu = (const unsigned*)&v0;
                #pragma unroll
                for (int q = 0; q < 4; q++) {
                    acc[2*q]   += __uint_as_float(uu[q] << 16);
                    acc[2*q+1] += __uint_as_float(uu[q] & 0xffff0000u);
                }
            }
            if (i < end && half == 0) {
                int s0 = csr[i];
                int4 v0 = *(const int4*)(base + (size_t)s0 * 256);
                const unsigned* uu = (const unsigned*)&v0;
                #pragma unroll
                for (int q = 0; q < 4; q++) {
                    acc[2*q]   += __uint_as_float(uu[q] << 16);
                    acc[2*q+1] += __uint_as_float(uu[q] & 0xffff0000u);
                }
            }
            #pragma unroll
            for (int q = 0; q < 8; q++) acc[q] += __shfl_xor(acc[q], 32);
            if (half == 0) {
                float scale = 1.f / fmaxf((float)(end - beg), 1.f);
                ushort_t o[8];
                #pragma unroll
                for (int q = 0; q < 8; q++) o[q] = f2b(acc[q] * scale);
                // Ms: sub-tile ki=c>>3 (64x64), row r, phys chunk (c&7)^(r&7)
                *(bf16x8*)&u.s.Ms[(c >> 3) * 4096 + r * 64 + ((c & 7) ^ (r & 7)) * 8] =
                    *(const bf16x8*)o;
            }
        }
    }

    // ---------- phase 2: GEMM ----------
    f32x4 acc[4][4];
    #pragma unroll
    for (int i = 0; i < 4; i++)
        #pragma unroll
        for (int j = 0; j < 4; j++)
            acc[i][j] = (f32x4){0.f, 0.f, 0.f, 0.f};

    const ushort_t* Ag = xsrc + (size_t)rowbase * 256;

    for (int ki = 0; ki < 8; ki++) {
        __syncthreads();   // prev LDS reads done (ki=0: phase-1 Ms writes visible)
        if (ki >= 4) {
            int kb = (ki - 4) * 64;
            #pragma unroll
            for (int t = 0; t < 2; t++) {
                int instr = wave * 2 + t;
                int flat = instr * 64 + lane;
                int row = flat >> 3, cc = flat & 7;
                int ccg = cc ^ (row & 7);
                load16(Ag + (size_t)row * 256 + kb + ccg * 8, &u.s.As[instr * 512]);
            }
        }
        {
            int kb = ki * 64;
            #pragma unroll
            for (int t = 0; t < 8; t++) {
                int instr = wave * 8 + t;
                int flat = instr * 64 + lane;
                int row = flat >> 3, cc = flat & 7;
                int ccg = cc ^ (row & 7);
                load16(W + (size_t)row * 512 + kb + ccg * 8, &u.s.Bs[instr * 512]);
            }
        }
        __syncthreads();   // vmcnt drain + barrier

        const ushort_t* Abase = (ki < 4) ? &u.s.Ms[ki * 4096] : u.s.As;
        #pragma unroll
        for (int ks = 0; ks < 2; ks++) {
            int cbase = ks * 4 + quad;
            bf16x8 af[4], bfr[4];
            #pragma unroll
            for (int rt = 0; rt < 4; rt++) {
                int r = rt * 16 + m16;
                af[rt] = *(const bf16x8*)&Abase[r * 64 + (cbase ^ swz) * 8];
            }
            #pragma unroll
            for (int ct = 0; ct < 4; ct++) {
                int r = wave * 64 + ct * 16 + m16;
                bfr[ct] = *(const bf16x8*)&u.s.Bs[r * 64 + (cbase ^ swz) * 8];
            }
            #pragma unroll
            for (int rt = 0; rt < 4; rt++)
                #pragma unroll
                for (int ct = 0; ct < 4; ct++)
                    acc[rt][ct] = __builtin_amdgcn_mfma_f32_16x16x32_bf16(
                        af[rt], bfr[ct], acc[rt][ct], 0, 0, 0);
        }
    }

    // ---------- epilogue: bias + rowsq + normalize + coalesced store ----------
    float bvals[4];
    #pragma unroll
    for (int ct = 0; ct < 4; ct++)
        bvals[ct] = bias[wave * 64 + ct * 16 + m16];
    #pragma unroll
    for (int rt = 0; rt < 4; rt++) {
        #pragma unroll
        for (int reg = 0; reg < 4; reg++) {
            float s = 0.f;
            #pragma unroll
            for (int ct = 0; ct < 4; ct++) {
                float v = acc[rt][ct][reg] + bvals[ct];
                acc[rt][ct][reg] = v;
                s += v * v;
            }
            #pragma unroll
            for (int off = 1; off < 16; off <<= 1)
                s += __shfl_xor(s, off);
            if (m16 == 0)
                atomicAdd(&rowsq[rt * 16 + quad * 4 + reg], s);
        }
    }
    __syncthreads();   // rowsq done; all LDS reads done -> ebuf reuse safe

    #pragma unroll
    for (int rt = 0; rt < 4; rt++) {
        #pragma unroll
        for (int reg = 0; reg < 4; reg++) {
            int rl = rt * 16 + quad * 4 + reg;
            float inv = 1.f / fmaxf(sqrtf(rowsq[rl]), 1e-12f);
            #pragma unroll
            for (int ct = 0; ct < 4; ct++) {
                float v = acc[rt][ct][reg] * inv;
                if (relu) v = fmaxf(v, 0.f);
                int col = wave * 64 + ct * 16 + m16;
                u.ebuf[rl * 264 + col] = f2b(v);
            }
        }
    }
    __syncthreads();

    #pragma unroll
    for (int j = 0; j < 8; j++) {
        int flat = j * 256 + tid;          // 2048 chunks = 64 rows x 32
        int row = flat >> 5, cc = flat & 31;
        int gr = rowbase + row;
        if (gr < N) {
            bf16x8 v = *(const bf16x8*)&u.ebuf[row * 264 + cc * 8];
            if (outf) {
                float4 f0, f1;
                f0.x = b2f((ushort_t)v[0]); f0.y = b2f((ushort_t)v[1]);
                f0.z = b2f((ushort_t)v[2]); f0.w = b2f((ushort_t)v[3]);
                f1.x = b2f((ushort_t)v[4]); f1.y = b2f((ushort_t)v[5]);
                f1.z = b2f((ushort_t)v[6]); f1.w = b2f((ushort_t)v[7]);
                float* ptr = outf + (size_t)gr * 256 + cc * 8;
                *(float4*)ptr = f0;
                *(float4*)(ptr + 4) = f1;
            } else {
                *(bf16x8*)(outb + (size_t)gr * 256 + cc * 8) = v;
            }
        }
    }
}

// ---------------- launch ----------------

static inline size_t align_up(size_t x, size_t a) { return (x + a - 1) & ~(a - 1); }

extern "C" void kernel_launch(void* const* d_in, const int* in_sizes, int n_in,
                              void* d_out, int out_size, void* d_ws, size_t ws_size,
                              hipStream_t stream) {
    const float* x   = (const float*)d_in[0];
    const int*   ei  = (const int*)d_in[1];
    const float* W1l = (const float*)d_in[2];
    const float* b1l = (const float*)d_in[3];
    const float* W1r = (const float*)d_in[4];
    const float* W2l = (const float*)d_in[5];
    const float* b2l = (const float*)d_in[6];
    const float* W2r = (const float*)d_in[7];

    int N = in_sizes[0] / DD;
    int E = in_sizes[1] / 2;
    int nbuck = (N + NPB - 1) / NPB;   // <= 512

    char* ws = (char*)d_ws;
    size_t off = 0;
    int* cnt = (int*)(ws + off);      off = align_up(off + (size_t)N * 4, 256);
    int* offs = (int*)(ws + off);     off = align_up(off + (size_t)(N + 1) * 4, 256);
    int* bcur = (int*)(ws + off);     off = align_up(off + (size_t)512 * 4, 256);
    int* part = (int*)(ws + off);     off = align_up(off + (size_t)64 * 4, 256);
    int* csr = (int*)(ws + off);      off = align_up(off + (size_t)E * 4, 256);
    int2* stage = (int2*)(ws + off);  off = align_up(off + (size_t)E * 8, 256);
    ushort_t* xb = (ushort_t*)(ws + off);  off = align_up(off + (size_t)N * 256 * 2, 256);
    ushort_t* hb = (ushort_t*)(ws + off);  off = align_up(off + (size_t)N * 256 * 2, 256);
    // A-tile staging overreads <=63 rows past N: xb spills into hb, hb into
    // wc1 — both harmless scratch.
    ushort_t* wc1 = (ushort_t*)(ws + off);   off = align_up(off + (size_t)256 * 512 * 2, 256);
    ushort_t* wc2 = (ushort_t*)(ws + off);   off = align_up(off + (size_t)256 * 512 * 2, 256);

    hipMemsetAsync(cnt, 0, (size_t)N * 4, stream);

    int xe = N * DD;
    int eb = (E + 255) / 256;
    int cxb = (xe / 8 + 255) / 256;
    int cwb = (4 * DD * DD / 8) / 256;
    prep_kernel<<<eb + cxb + cwb, 256, 0, stream>>>(ei, cnt, E, eb,
                                                    x, xb, xe, cxb,
                                                    W1l, W1r, W2l, W2r, wc1, wc2);

    int nb = (N + 2047) / 2048;   // <= 64
    scan_partial_kernel<<<nb, 256, 0, stream>>>(cnt, part, N);
    scan_final_kernel<<<nb, 256, 0, stream>>>(cnt, part, offs, bcur, N, E, nb);

    int pb = (E + 2047) / 2048;
    part_kernel<<<pb, 256, 0, stream>>>(ei, bcur, stage, E, nbuck);
    group_kernel<<<nbuck, 256, 0, stream>>>(stage, offs, csr, N);

    int gb = (N + 63) / 64;

    // layer 1: fused gather+GEMM -> hb (bf16, relu)
    sage_layer_kernel<<<gb, 256, 0, stream>>>(xb, csr, offs, wc1, b1l,
                                              hb, (float*)nullptr, N, 1);
    // layer 2: fused gather+GEMM -> d_out (fp32)
    sage_layer_kernel<<<gb, 256, 0, stream>>>(hb, csr, offs, wc2, b2l,
                                              (ushort_t*)nullptr, (float*)d_out, N, 0);
}